// Round 7
// baseline (331.203 us; speedup 1.0000x reference)
//
#include <hip/hip_runtime.h>
#include <math.h>

constexpr int BATCH = 8;
constexpr int NC    = 384;
constexpr int H     = 56, W = 56, HW = 3136;
constexpr int NPTS  = 784;          // 28*28
constexpr int NG    = 4, GC = 96;
constexpr int NH    = 8, HC = 48;

typedef __attribute__((ext_vector_type(8))) short short8;
typedef __attribute__((ext_vector_type(4))) float f32x4;
typedef __attribute__((ext_vector_type(4))) unsigned short us4;

__device__ inline unsigned short f2bf(float f) {       // RNE
    union { float f; unsigned u; } v; v.f = f;
    unsigned r = v.u + 0x7FFF + ((v.u >> 16) & 1);
    return (unsigned short)(r >> 16);
}
__device__ inline unsigned short f2bf_t(float f) {     // truncate (1 op)
    union { float f; unsigned u; } v; v.f = f;
    return (unsigned short)(v.u >> 16);
}
__device__ inline float bf2f(unsigned short u) {
    union { unsigned u; float f; } v; v.u = (unsigned)u << 16;
    return v.f;
}
__device__ inline float wred_sum(float v) {
    #pragma unroll
    for (int off = 32; off > 0; off >>= 1) v += __shfl_xor(v, off);
    return v;
}

// ---------------------------------------------------------------------------
// Transpose+convert: x [b][384][3136] fp32 -> xT [b][3136][384] bf16
// ---------------------------------------------------------------------------
__global__ __launch_bounds__(256) void transpose_cvt(
    const float* __restrict__ x, unsigned short* __restrict__ xT)
{
    __shared__ unsigned short Ls[64 * 68];
    int b = blockIdx.z, c0 = blockIdx.y * 64, hw0 = blockIdx.x * 64;
    const float* xb = x + ((size_t)b * NC + c0) * HW + hw0;
    int t = threadIdx.x;
    #pragma unroll
    for (int i = 0; i < 4; i++) {
        int u = t + i * 256;
        int cc = u >> 4, f4 = (u & 15) * 4;
        float4 v = *(const float4*)&xb[(size_t)cc * HW + f4];
        us4 p; p[0] = f2bf(v.x); p[1] = f2bf(v.y); p[2] = f2bf(v.z); p[3] = f2bf(v.w);
        *(us4*)&Ls[cc * 68 + f4] = p;
    }
    __syncthreads();
    unsigned short* xTb = xT + ((size_t)b * HW + hw0) * NC + c0;
    #pragma unroll
    for (int i = 0; i < 4; i++) {
        int u = t + i * 256;
        int hw = u >> 4, cg = (u & 15) * 4;
        us4 p;
        p[0] = Ls[(cg + 0) * 68 + hw];
        p[1] = Ls[(cg + 1) * 68 + hw];
        p[2] = Ls[(cg + 2) * 68 + hw];
        p[3] = Ls[(cg + 3) * 68 + hw];
        *(us4*)&xTb[(size_t)hw * NC + cg] = p;
    }
}

// ---------------------------------------------------------------------------
// Weight convert: Wq -> wqb, Wk -> wkv[0:384], Wv -> wkv[384:768], Wo -> wob
// ---------------------------------------------------------------------------
__global__ __launch_bounds__(256) void wcvt(
    const float* __restrict__ w0, const float* __restrict__ w1,
    const float* __restrict__ w2, const float* __restrict__ w3,
    unsigned short* __restrict__ o0, unsigned short* __restrict__ okv,
    unsigned short* __restrict__ o3)
{
    const float* src; unsigned short* dst;
    switch (blockIdx.y) {
        case 0: src = w0; dst = o0; break;
        case 1: src = w1; dst = okv; break;
        case 2: src = w2; dst = okv + NC * NC; break;
        default: src = w3; dst = o3; break;
    }
    int idx = (blockIdx.x * 256 + threadIdx.x) * 4;
    float4 v = *(const float4*)&src[idx];
    us4 p; p[0] = f2bf(v.x); p[1] = f2bf(v.y); p[2] = f2bf(v.z); p[3] = f2bf(v.w);
    *(us4*)&dst[idx] = p;
}

// ---------------------------------------------------------------------------
// bf16 MFMA GEMM: C[b][m][n] = A[m][k] * BT[b][n][k]^T + bias[m]
// MODE 0: fp32 out [m][n]
// MODE 2: bf16 T-out [n][384]
// MODE 4: fused KV (A is 768 rows): m<384 -> KT[n][384] (bias), m>=384 ->
//         V[m-384][n] (bias2) into Cb2
// ---------------------------------------------------------------------------
template<int MODE>
__global__ __launch_bounds__(256) void gemm_bf16(
    const unsigned short* __restrict__ A, const float* __restrict__ bias,
    const float* __restrict__ bias2, const unsigned short* __restrict__ BT,
    float* __restrict__ Cf, unsigned short* __restrict__ Cb,
    unsigned short* __restrict__ Cb2, int N)
{
    int b  = blockIdx.z;
    int n0 = blockIdx.x * 128;
    int m0 = blockIdx.y * 128;
    const unsigned short* BTb = BT + (size_t)b * N * NC;

    __shared__ unsigned short As[128 * 40];
    __shared__ unsigned short Bs[128 * 40];

    int t = threadIdx.x;
    int wave = t >> 6, lane = t & 63;
    int quad = lane >> 4, col = lane & 15;
    int wm = (wave >> 1) * 64, wn = (wave & 1) * 64;

    const short8 z8 = {0,0,0,0,0,0,0,0};
    f32x4 acc[4][4];
    #pragma unroll
    for (int i = 0; i < 4; i++)
        #pragma unroll
        for (int j = 0; j < 4; j++) acc[i][j] = (f32x4){0.f, 0.f, 0.f, 0.f};

    for (int k0 = 0; k0 < NC; k0 += 32) {
        #pragma unroll
        for (int i = 0; i < 2; i++) {
            int u = t + i * 256;
            int mm = u >> 2, kc = (u & 3) * 8;
            *(short8*)&As[mm * 40 + kc] =
                *(const short8*)&A[(size_t)(m0 + mm) * NC + k0 + kc];
        }
        #pragma unroll
        for (int i = 0; i < 2; i++) {
            int u = t + i * 256;
            int nn = u >> 2, kc = (u & 3) * 8;
            short8 val = z8;
            if (n0 + nn < N)
                val = *(const short8*)&BTb[(size_t)(n0 + nn) * NC + k0 + kc];
            *(short8*)&Bs[nn * 40 + kc] = val;
        }
        __syncthreads();

        short8 af[4], bf[4];
        #pragma unroll
        for (int mt = 0; mt < 4; mt++)
            af[mt] = *(const short8*)&As[(wm + mt * 16 + col) * 40 + quad * 8];
        #pragma unroll
        for (int nt = 0; nt < 4; nt++)
            bf[nt] = *(const short8*)&Bs[(wn + nt * 16 + col) * 40 + quad * 8];
        #pragma unroll
        for (int mt = 0; mt < 4; mt++)
            #pragma unroll
            for (int nt = 0; nt < 4; nt++)
                acc[mt][nt] = __builtin_amdgcn_mfma_f32_16x16x32_bf16(
                    af[mt], bf[nt], acc[mt][nt], 0, 0, 0);
        __syncthreads();
    }

    if constexpr (MODE == 0) {
        float* Cfb = Cf + (size_t)b * NC * N;
        #pragma unroll
        for (int mt = 0; mt < 4; mt++) {
            #pragma unroll
            for (int r = 0; r < 4; r++) {
                int m = m0 + wm + mt * 16 + quad * 4 + r;
                float bv = bias[m];
                #pragma unroll
                for (int nt = 0; nt < 4; nt++) {
                    int n = n0 + wn + nt * 16 + col;
                    if (n < N) Cfb[(size_t)m * N + n] = acc[mt][nt][r] + bv;
                }
            }
        }
    } else if constexpr (MODE == 2) {
        unsigned short* Kb = Cb + (size_t)b * N * NC;
        #pragma unroll
        for (int mt = 0; mt < 4; mt++) {
            int mb = m0 + wm + mt * 16 + quad * 4;
            float bv[4];
            #pragma unroll
            for (int r = 0; r < 4; r++) bv[r] = bias[mb + r];
            #pragma unroll
            for (int nt = 0; nt < 4; nt++) {
                int n = n0 + wn + nt * 16 + col;
                if (n < N) {
                    us4 p;
                    #pragma unroll
                    for (int r = 0; r < 4; r++) p[r] = f2bf(acc[mt][nt][r] + bv[r]);
                    *(us4*)&Kb[(size_t)n * NC + mb] = p;
                }
            }
        }
    } else {   // MODE 4: fused KV
        if (m0 < NC) {     // K rows -> KT[n][384]
            unsigned short* Kb = Cb + (size_t)b * N * NC;
            #pragma unroll
            for (int mt = 0; mt < 4; mt++) {
                int mb = m0 + wm + mt * 16 + quad * 4;
                float bv[4];
                #pragma unroll
                for (int r = 0; r < 4; r++) bv[r] = bias[mb + r];
                #pragma unroll
                for (int nt = 0; nt < 4; nt++) {
                    int n = n0 + wn + nt * 16 + col;
                    if (n < N) {
                        us4 p;
                        #pragma unroll
                        for (int r = 0; r < 4; r++) p[r] = f2bf(acc[mt][nt][r] + bv[r]);
                        *(us4*)&Kb[(size_t)n * NC + mb] = p;
                    }
                }
            }
        } else {           // V rows -> V[m-384][n]
            unsigned short* Vb = Cb2 + (size_t)b * NC * N;
            #pragma unroll
            for (int mt = 0; mt < 4; mt++) {
                #pragma unroll
                for (int r = 0; r < 4; r++) {
                    int m = m0 - NC + wm + mt * 16 + quad * 4 + r;
                    float bv = bias2[m];
                    #pragma unroll
                    for (int nt = 0; nt < 4; nt++) {
                        int n = n0 + wn + nt * 16 + col;
                        if (n < N) Vb[(size_t)m * N + n] = f2bf(acc[mt][nt][r] + bv);
                    }
                }
            }
        }
    }
}

// ---------------------------------------------------------------------------
// Offset net, wave-per-point (unchanged)
// ---------------------------------------------------------------------------
__global__ __launch_bounds__(256) void offset_kernel(
    const unsigned short* __restrict__ qT, const float* __restrict__ dww,
    const float* __restrict__ dwb, const float* __restrict__ lng,
    const float* __restrict__ lnb, const float* __restrict__ pww,
    float* __restrict__ pos_out,   float* __restrict__ ref_out)
{
    int wave = threadIdx.x >> 6, l = threadIdx.x & 63;
    int bg = blockIdx.y, b = bg >> 2, g = bg & 3;
    int s  = blockIdx.x * 4 + wave;
    int py = s / 28, px = s - py * 28;
    bool has2 = l < 32;
    int c0 = l, c1 = 64 + l;

    const unsigned short* qb = qT + (size_t)b * HW * NC + g * GC;

    float h0 = 0.f, h1 = 0.f;
    #pragma unroll
    for (int ky = 0; ky < 3; ky++) {
        int yy = py * 2 - 1 + ky;
        if (yy < 0 || yy >= H) continue;
        #pragma unroll
        for (int kx = 0; kx < 3; kx++) {
            int xx = px * 2 - 1 + kx;
            if (xx < 0 || xx >= W) continue;
            const unsigned short* row = qb + (size_t)(yy * W + xx) * NC;
            float w0 = dww[c0 * 9 + ky * 3 + kx];
            h0 = fmaf(bf2f(row[c0]), w0, h0);
            if (has2) {
                float w1 = dww[c1 * 9 + ky * 3 + kx];
                h1 = fmaf(bf2f(row[c1]), w1, h1);
            }
        }
    }
    h0 += dwb[c0];
    if (has2) h1 += dwb[c1];

    float mu = wred_sum(h0 + (has2 ? h1 : 0.f)) * (1.f / GC);
    float d0 = h0 - mu, d1 = h1 - mu;
    float var = wred_sum(d0 * d0 + (has2 ? d1 * d1 : 0.f)) * (1.f / GC);
    float rstd = rsqrtf(var + 1e-5f);

    float hn0 = d0 * rstd * lng[c0] + lnb[c0];
    float ge0 = 0.5f * hn0 * (1.f + erff(hn0 * 0.70710678118654752f));
    float ge1 = 0.f;
    if (has2) {
        float hn1 = d1 * rstd * lng[c1] + lnb[c1];
        ge1 = 0.5f * hn1 * (1.f + erff(hn1 * 0.70710678118654752f));
    }

    float offy = wred_sum(ge0 * pww[c0] + (has2 ? ge1 * pww[c1] : 0.f));
    float offx = wred_sum(ge0 * pww[GC + c0] + (has2 ? ge1 * pww[GC + c1] : 0.f));

    if (l == 0) {
        float ry = (2.f * py + 1.f) / 27.f - 1.f;
        float rx = (2.f * px + 1.f) / 27.f - 1.f;
        size_t idx = ((size_t)bg * NPTS + s) * 2;
        pos_out[idx]     = tanhf(offy) * (1.f / 27.f) + ry;
        pos_out[idx + 1] = tanhf(offx) * (1.f / 27.f) + rx;
        ref_out[idx]     = ry;
        ref_out[idx + 1] = rx;
    }
}

// ---------------------------------------------------------------------------
// Bilinear grid sample from xT (bf16, [b][hw][384]) -> xsT [b][pt][384] bf16.
// 4 corner reads per point are coalesced 64B row-segments.
// ---------------------------------------------------------------------------
__global__ __launch_bounds__(256) void sample_kernel(
    const unsigned short* __restrict__ xT, const float* __restrict__ pos,
    unsigned short* __restrict__ xsT)
{
    int bg = blockIdx.y;
    int b  = bg >> 2, g = bg & 3;
    int s  = blockIdx.x * 8 + (threadIdx.x >> 5);
    int l  = threadIdx.x & 31;

    const float* pg = pos + ((size_t)bg * NPTS + s) * 2;
    float py = pg[0], px = pg[1];
    float gx = (px + 1.f) * 27.5f;
    float gy = (py + 1.f) * 27.5f;
    float x0f = floorf(gx), y0f = floorf(gy);
    int ix0 = (int)x0f, iy0 = (int)y0f;
    int ix1 = ix0 + 1,  iy1 = iy0 + 1;
    float wx1 = gx - x0f, wx0 = 1.f - wx1;
    float wy1 = gy - y0f, wy0 = 1.f - wy1;
    bool vx0 = (ix0 >= 0) && (ix0 < W);
    bool vx1 = (ix1 >= 0) && (ix1 < W);
    bool vy0 = (iy0 >= 0) && (iy0 < H);
    bool vy1 = (iy1 >= 0) && (iy1 < H);
    int cx0 = vx0 ? ix0 : 0, cx1 = vx1 ? ix1 : 0;
    int cy0 = vy0 ? iy0 : 0, cy1 = vy1 ? iy1 : 0;
    float w00 = (vx0 && vy0) ? wx0 * wy0 : 0.f;
    float w01 = (vx1 && vy0) ? wx1 * wy0 : 0.f;
    float w10 = (vx0 && vy1) ? wx0 * wy1 : 0.f;
    float w11 = (vx1 && vy1) ? wx1 * wy1 : 0.f;

    const unsigned short* xb = xT + (size_t)b * HW * NC + g * GC;
    const unsigned short* r00 = xb + (size_t)(cy0 * W + cx0) * NC;
    const unsigned short* r01 = xb + (size_t)(cy0 * W + cx1) * NC;
    const unsigned short* r10 = xb + (size_t)(cy1 * W + cx0) * NC;
    const unsigned short* r11 = xb + (size_t)(cy1 * W + cx1) * NC;
    unsigned short* orow = xsT + ((size_t)b * NPTS + s) * NC + g * GC;
    #pragma unroll
    for (int ci = 0; ci < 3; ci++) {
        int c = l + ci * 32;
        float val = bf2f(r00[c]) * w00 + bf2f(r01[c]) * w01
                  + bf2f(r10[c]) * w10 + bf2f(r11[c]) * w11;
        orow[c] = f2bf(val);
    }
}

// ---------------------------------------------------------------------------
// Fused flash attention v4: K/V fragments loaded DIRECTLY from global
// (L1/L2-resident row-segments of KT and VT) — no K/V LDS, no barriers.
// LDS holds only wave-private P panes (10 KB). 32 queries/wave, no
// max-subtraction (shift-invariant, |s| small), scale pre-folded in Q.
// 784 = 49*16 -> per-16-key-tile validity is wave-uniform; clamped loads
// for the padded tail read finite real data and P=0 kills their PV term.
// ---------------------------------------------------------------------------
#define PS_STRIDE 40    // shorts: 32 keys + 8 pad (per-set pane)

__device__ inline short8 scale8(short8 v, float s) {
    short8 r;
    #pragma unroll
    for (int j = 0; j < 8; j++)
        r[j] = (short)f2bf(bf2f((unsigned short)v[j]) * s);
    return r;
}

__global__ __launch_bounds__(256) void attn_mfma(
    const unsigned short* __restrict__ qT, const unsigned short* __restrict__ kt,
    const unsigned short* __restrict__ vt, unsigned short* __restrict__ aoT)
{
    __shared__ __align__(16) unsigned short Ps[8 * 16 * PS_STRIDE];  // 10240 B

    int t    = threadIdx.x;
    int wave = t >> 6, lane = t & 63;
    int quad = lane >> 4, col = lane & 15;

    int bh = blockIdx.y;
    int b  = bh >> 3, h = bh & 7;
    int m0 = blockIdx.x * 128;
    const unsigned short* KT = kt + (size_t)b * NPTS * NC + h * HC;
    const unsigned short* VT = vt + ((size_t)b * NC + h * HC) * NPTS;

    const float scale = 0.14433756729740643f;   // 48^-0.5
    const short8 z8 = {0,0,0,0,0,0,0,0};

    // ---- Q B-fragments, 2 sets, pre-scaled ----
    int gm0 = m0 + wave * 32 + col;
    int gm1 = gm0 + 16;
    short8 qb0[2], qb1[2];
    {
        int cg0 = gm0 < HW ? gm0 : HW - 1;
        int cg1 = gm1 < HW ? gm1 : HW - 1;
        const unsigned short* r0 = qT + ((size_t)b * HW + cg0) * NC + h * HC;
        const unsigned short* r1 = qT + ((size_t)b * HW + cg1) * NC + h * HC;
        qb0[0] = scale8(*(const short8*)&r0[quad * 8], scale);
        qb0[1] = scale8(*(const short8*)&r1[quad * 8], scale);
        if (quad < 2) {
            qb1[0] = scale8(*(const short8*)&r0[32 + quad * 8], scale);
            qb1[1] = scale8(*(const short8*)&r1[32 + quad * 8], scale);
        } else { qb1[0] = z8; qb1[1] = z8; }
    }

    unsigned short* pane0 = Ps + (wave * 2 + 0) * 16 * PS_STRIDE;
    unsigned short* pane1 = Ps + (wave * 2 + 1) * 16 * PS_STRIDE;

    float l_acc[2] = {0.f, 0.f};
    f32x4 acc_o[2][3];
    #pragma unroll
    for (int s2 = 0; s2 < 2; s2++)
        #pragma unroll
        for (int ct = 0; ct < 3; ct++) acc_o[s2][ct] = (f32x4){0.f, 0.f, 0.f, 0.f};

    for (int ci = 0; ci < 7; ci++) {
        int k0 = ci * 128;

        #pragma unroll
        for (int s2 = 0; s2 < 4; s2++) {
            // ---- S^T tiles (K frags straight from global) + streaming exp --
            #pragma unroll
            for (int jth = 0; jth < 2; jth++) {
                int jt = s2 * 2 + jth;
                int key = k0 + jt * 16 + col;
                key = key < NPTS ? key : NPTS - 1;          // clamp (finite data)
                const unsigned short* krow = KT + (size_t)key * NC;
                short8 kb0 = *(const short8*)&krow[quad * 8];
                short8 kb1 = (quad < 2) ? *(const short8*)&krow[32 + quad * 8] : z8;
                bool valid = (k0 + jt * 16) < NPTS;         // tile-uniform
                #pragma unroll
                for (int set = 0; set < 2; set++) {
                    f32x4 sa = {0.f, 0.f, 0.f, 0.f};
                    sa = __builtin_amdgcn_mfma_f32_16x16x32_bf16(kb0, qb0[set], sa, 0, 0, 0);
                    sa = __builtin_amdgcn_mfma_f32_16x16x32_bf16(kb1, qb1[set], sa, 0, 0, 0);
                    us4 p = {0, 0, 0, 0};
                    if (valid) {
                        #pragma unroll
                        for (int r = 0; r < 4; r++) {
                            float pv = __expf(sa[r]);
                            l_acc[set] += pv;
                            p[r] = f2bf_t(pv);
                        }
                    }
                    unsigned short* pane = set ? pane1 : pane0;
                    *(us4*)&pane[col * PS_STRIDE + jth * 16 + quad * 4] = p;
                }
            }
            // ---- PV: V frags straight from global, P from wave-private LDS -
            short8 pb0 = *(const short8*)&pane0[col * PS_STRIDE + quad * 8];
            short8 pb1 = *(const short8*)&pane1[col * PS_STRIDE + quad * 8];
            int voff = k0 + s2 * 32 + quad * 8;
            voff = voff <= (NPTS - 8) ? voff : (NPTS - 8);  // clamp (finite data)
            #pragma unroll
            for (int ct = 0; ct < 3; ct++) {
                short8 va = *(const short8*)&VT[(size_t)(ct * 16 + col) * NPTS + voff];
                acc_o[0][ct] = __builtin_amdgcn_mfma_f32_16x16x32_bf16(va, pb0, acc_o[0][ct], 0, 0, 0);
                acc_o[1][ct] = __builtin_amdgcn_mfma_f32_16x16x32_bf16(va, pb1, acc_o[1][ct], 0, 0, 0);
            }
        }
    }

    // ---- epilogue: cross-quad l reduction, normalize, us4 stores ----
    #pragma unroll
    for (int set = 0; set < 2; set++) {
        float l = l_acc[set];
        l += __shfl_xor(l, 16);
        l += __shfl_xor(l, 32);
        float inv = 1.f / l;
        int gm = set ? gm1 : gm0;
        if (gm < HW) {
            unsigned short* orow = aoT + ((size_t)b * HW + gm) * NC + h * HC;
            #pragma unroll
            for (int ct = 0; ct < 3; ct++) {
                us4 p;
                #pragma unroll
                for (int r = 0; r < 4; r++) p[r] = f2bf(acc_o[set][ct][r] * inv);
                *(us4*)&orow[ct * 16 + quad * 4] = p;
            }
        }
    }
}

// ---------------------------------------------------------------------------
extern "C" void kernel_launch(void* const* d_in, const int* in_sizes, int n_in,
                              void* d_out, int out_size, void* d_ws, size_t ws_size,
                              hipStream_t stream)
{
    const float* x   = (const float*)d_in[0];
    const float* Wq  = (const float*)d_in[1];
    const float* bq  = (const float*)d_in[2];
    const float* Wk  = (const float*)d_in[3];
    const float* bk  = (const float*)d_in[4];
    const float* Wv  = (const float*)d_in[5];
    const float* bv  = (const float*)d_in[6];
    const float* Wo  = (const float*)d_in[7];
    const float* bo  = (const float*)d_in[8];
    const float* dww = (const float*)d_in[9];
    const float* dwb = (const float*)d_in[10];
    const float* lng = (const float*)d_in[11];
    const float* lnb = (const float*)d_in[12];
    const float* pww = (const float*)d_in[13];

    float* out     = (float*)d_out;
    float* y_out   = out;
    float* pos_out = out + (size_t)BATCH * NC * HW;
    float* ref_out = pos_out + (size_t)BATCH * NG * NPTS * 2;

    const size_t NBIG = (size_t)BATCH * NC * HW;    // 9,633,792
    const size_t NSML = (size_t)BATCH * NC * NPTS;  // 2,408,448

    unsigned short* xT   = (unsigned short*)d_ws;
    unsigned short* qT   = xT   + NBIG;
    unsigned short* xsT  = qT   + NBIG;
    unsigned short* kt_w = xsT  + NSML;
    unsigned short* vt_w = kt_w + NSML;
    unsigned short* aoT  = vt_w + NSML;
    unsigned short* wqb  = aoT  + NBIG;
    unsigned short* wob  = wqb + NC * NC;
    unsigned short* wkv  = wob + NC * NC;          // 768 x 384

    transpose_cvt<<<dim3(49, 6, BATCH), 256, 0, stream>>>(x, xT);
    wcvt<<<dim3(144, 4), 256, 0, stream>>>(Wq, Wk, Wv, Wo, wqb, wkv, wob);
    gemm_bf16<2><<<dim3(25, 3, BATCH), 256, 0, stream>>>(
        wqb, bq, nullptr, xT, nullptr, qT, nullptr, HW);
    offset_kernel<<<dim3(196, BATCH * NG), 256, 0, stream>>>(
        qT, dww, dwb, lng, lnb, pww, pos_out, ref_out);
    sample_kernel<<<dim3(98, BATCH * NG), 256, 0, stream>>>(xT, pos_out, xsT);
    gemm_bf16<4><<<dim3(7, 6, BATCH), 256, 0, stream>>>(
        wkv, bk, bv, xsT, nullptr, kt_w, vt_w, NPTS);
    attn_mfma<<<dim3((HW + 127) / 128, BATCH * NH), 256, 0, stream>>>(
        qT, kt_w, vt_w, aoT);
    gemm_bf16<0><<<dim3(25, 3, BATCH), 256, 0, stream>>>(
        wob, bo, nullptr, aoT, y_out, nullptr, nullptr, HW);
}

// Round 8
// 324.858 us; speedup vs baseline: 1.0195x; 1.0195x over previous
//
#include <hip/hip_runtime.h>
#include <math.h>

constexpr int BATCH = 8;
constexpr int NC    = 384;
constexpr int H     = 56, W = 56, HW = 3136;
constexpr int NPTS  = 784;          // 28*28
constexpr int NG    = 4, GC = 96;
constexpr int NH    = 8, HC = 48;

typedef __attribute__((ext_vector_type(8))) short short8;
typedef __attribute__((ext_vector_type(4))) float f32x4;
typedef __attribute__((ext_vector_type(4))) unsigned short us4;

__device__ inline unsigned short f2bf(float f) {       // RNE
    union { float f; unsigned u; } v; v.f = f;
    unsigned r = v.u + 0x7FFF + ((v.u >> 16) & 1);
    return (unsigned short)(r >> 16);
}
__device__ inline unsigned short f2bf_t(float f) {     // truncate (1 op)
    union { float f; unsigned u; } v; v.f = f;
    return (unsigned short)(v.u >> 16);
}
__device__ inline float bf2f(unsigned short u) {
    union { unsigned u; float f; } v; v.u = (unsigned)u << 16;
    return v.f;
}
__device__ inline float wred_sum(float v) {
    #pragma unroll
    for (int off = 32; off > 0; off >>= 1) v += __shfl_xor(v, off);
    return v;
}

// ---------------------------------------------------------------------------
// Transpose+convert: x [b][384][3136] fp32 -> xT [b][3136][384] bf16
// ---------------------------------------------------------------------------
__global__ __launch_bounds__(256) void transpose_cvt(
    const float* __restrict__ x, unsigned short* __restrict__ xT)
{
    __shared__ unsigned short Ls[64 * 68];
    int b = blockIdx.z, c0 = blockIdx.y * 64, hw0 = blockIdx.x * 64;
    const float* xb = x + ((size_t)b * NC + c0) * HW + hw0;
    int t = threadIdx.x;
    #pragma unroll
    for (int i = 0; i < 4; i++) {
        int u = t + i * 256;
        int cc = u >> 4, f4 = (u & 15) * 4;
        float4 v = *(const float4*)&xb[(size_t)cc * HW + f4];
        us4 p; p[0] = f2bf(v.x); p[1] = f2bf(v.y); p[2] = f2bf(v.z); p[3] = f2bf(v.w);
        *(us4*)&Ls[cc * 68 + f4] = p;
    }
    __syncthreads();
    unsigned short* xTb = xT + ((size_t)b * HW + hw0) * NC + c0;
    #pragma unroll
    for (int i = 0; i < 4; i++) {
        int u = t + i * 256;
        int hw = u >> 4, cg = (u & 15) * 4;
        us4 p;
        p[0] = Ls[(cg + 0) * 68 + hw];
        p[1] = Ls[(cg + 1) * 68 + hw];
        p[2] = Ls[(cg + 2) * 68 + hw];
        p[3] = Ls[(cg + 3) * 68 + hw];
        *(us4*)&xTb[(size_t)hw * NC + cg] = p;
    }
}

// ---------------------------------------------------------------------------
// Weight convert: Wq -> wqb, Wk -> wkv[0:384], Wv -> wkv[384:768], Wo -> wob
// ---------------------------------------------------------------------------
__global__ __launch_bounds__(256) void wcvt(
    const float* __restrict__ w0, const float* __restrict__ w1,
    const float* __restrict__ w2, const float* __restrict__ w3,
    unsigned short* __restrict__ o0, unsigned short* __restrict__ okv,
    unsigned short* __restrict__ o3)
{
    const float* src; unsigned short* dst;
    switch (blockIdx.y) {
        case 0: src = w0; dst = o0; break;
        case 1: src = w1; dst = okv; break;
        case 2: src = w2; dst = okv + NC * NC; break;
        default: src = w3; dst = o3; break;
    }
    int idx = (blockIdx.x * 256 + threadIdx.x) * 4;
    float4 v = *(const float4*)&src[idx];
    us4 p; p[0] = f2bf(v.x); p[1] = f2bf(v.y); p[2] = f2bf(v.z); p[3] = f2bf(v.w);
    *(us4*)&dst[idx] = p;
}

// ---------------------------------------------------------------------------
// bf16 MFMA GEMM: C[b][m][n] = A[m][k] * BT[b][n][k]^T + bias[m]
// MODE 0: fp32 out [m][n]
// MODE 2: bf16 T-out [n][384]
// MODE 4: fused KV (A is 768 rows): m<384 -> KT[n][384] (bias), m>=384 ->
//         V[m-384][n] (bias2) into Cb2
// ---------------------------------------------------------------------------
template<int MODE>
__global__ __launch_bounds__(256) void gemm_bf16(
    const unsigned short* __restrict__ A, const float* __restrict__ bias,
    const float* __restrict__ bias2, const unsigned short* __restrict__ BT,
    float* __restrict__ Cf, unsigned short* __restrict__ Cb,
    unsigned short* __restrict__ Cb2, int N)
{
    int b  = blockIdx.z;
    int n0 = blockIdx.x * 128;
    int m0 = blockIdx.y * 128;
    const unsigned short* BTb = BT + (size_t)b * N * NC;

    __shared__ unsigned short As[128 * 40];
    __shared__ unsigned short Bs[128 * 40];

    int t = threadIdx.x;
    int wave = t >> 6, lane = t & 63;
    int quad = lane >> 4, col = lane & 15;
    int wm = (wave >> 1) * 64, wn = (wave & 1) * 64;

    const short8 z8 = {0,0,0,0,0,0,0,0};
    f32x4 acc[4][4];
    #pragma unroll
    for (int i = 0; i < 4; i++)
        #pragma unroll
        for (int j = 0; j < 4; j++) acc[i][j] = (f32x4){0.f, 0.f, 0.f, 0.f};

    for (int k0 = 0; k0 < NC; k0 += 32) {
        #pragma unroll
        for (int i = 0; i < 2; i++) {
            int u = t + i * 256;
            int mm = u >> 2, kc = (u & 3) * 8;
            *(short8*)&As[mm * 40 + kc] =
                *(const short8*)&A[(size_t)(m0 + mm) * NC + k0 + kc];
        }
        #pragma unroll
        for (int i = 0; i < 2; i++) {
            int u = t + i * 256;
            int nn = u >> 2, kc = (u & 3) * 8;
            short8 val = z8;
            if (n0 + nn < N)
                val = *(const short8*)&BTb[(size_t)(n0 + nn) * NC + k0 + kc];
            *(short8*)&Bs[nn * 40 + kc] = val;
        }
        __syncthreads();

        short8 af[4], bf[4];
        #pragma unroll
        for (int mt = 0; mt < 4; mt++)
            af[mt] = *(const short8*)&As[(wm + mt * 16 + col) * 40 + quad * 8];
        #pragma unroll
        for (int nt = 0; nt < 4; nt++)
            bf[nt] = *(const short8*)&Bs[(wn + nt * 16 + col) * 40 + quad * 8];
        #pragma unroll
        for (int mt = 0; mt < 4; mt++)
            #pragma unroll
            for (int nt = 0; nt < 4; nt++)
                acc[mt][nt] = __builtin_amdgcn_mfma_f32_16x16x32_bf16(
                    af[mt], bf[nt], acc[mt][nt], 0, 0, 0);
        __syncthreads();
    }

    if constexpr (MODE == 0) {
        float* Cfb = Cf + (size_t)b * NC * N;
        #pragma unroll
        for (int mt = 0; mt < 4; mt++) {
            #pragma unroll
            for (int r = 0; r < 4; r++) {
                int m = m0 + wm + mt * 16 + quad * 4 + r;
                float bv = bias[m];
                #pragma unroll
                for (int nt = 0; nt < 4; nt++) {
                    int n = n0 + wn + nt * 16 + col;
                    if (n < N) Cfb[(size_t)m * N + n] = acc[mt][nt][r] + bv;
                }
            }
        }
    } else if constexpr (MODE == 2) {
        unsigned short* Kb = Cb + (size_t)b * N * NC;
        #pragma unroll
        for (int mt = 0; mt < 4; mt++) {
            int mb = m0 + wm + mt * 16 + quad * 4;
            float bv[4];
            #pragma unroll
            for (int r = 0; r < 4; r++) bv[r] = bias[mb + r];
            #pragma unroll
            for (int nt = 0; nt < 4; nt++) {
                int n = n0 + wn + nt * 16 + col;
                if (n < N) {
                    us4 p;
                    #pragma unroll
                    for (int r = 0; r < 4; r++) p[r] = f2bf(acc[mt][nt][r] + bv[r]);
                    *(us4*)&Kb[(size_t)n * NC + mb] = p;
                }
            }
        }
    } else {   // MODE 4: fused KV
        if (m0 < NC) {     // K rows -> KT[n][384]
            unsigned short* Kb = Cb + (size_t)b * N * NC;
            #pragma unroll
            for (int mt = 0; mt < 4; mt++) {
                int mb = m0 + wm + mt * 16 + quad * 4;
                float bv[4];
                #pragma unroll
                for (int r = 0; r < 4; r++) bv[r] = bias[mb + r];
                #pragma unroll
                for (int nt = 0; nt < 4; nt++) {
                    int n = n0 + wn + nt * 16 + col;
                    if (n < N) {
                        us4 p;
                        #pragma unroll
                        for (int r = 0; r < 4; r++) p[r] = f2bf(acc[mt][nt][r] + bv[r]);
                        *(us4*)&Kb[(size_t)n * NC + mb] = p;
                    }
                }
            }
        } else {           // V rows -> V[m-384][n]
            unsigned short* Vb = Cb2 + (size_t)b * NC * N;
            #pragma unroll
            for (int mt = 0; mt < 4; mt++) {
                #pragma unroll
                for (int r = 0; r < 4; r++) {
                    int m = m0 - NC + wm + mt * 16 + quad * 4 + r;
                    float bv = bias2[m];
                    #pragma unroll
                    for (int nt = 0; nt < 4; nt++) {
                        int n = n0 + wn + nt * 16 + col;
                        if (n < N) Vb[(size_t)m * N + n] = f2bf(acc[mt][nt][r] + bv);
                    }
                }
            }
        }
    }
}

// ---------------------------------------------------------------------------
// Offset net, wave-per-point (unchanged)
// ---------------------------------------------------------------------------
__global__ __launch_bounds__(256) void offset_kernel(
    const unsigned short* __restrict__ qT, const float* __restrict__ dww,
    const float* __restrict__ dwb, const float* __restrict__ lng,
    const float* __restrict__ lnb, const float* __restrict__ pww,
    float* __restrict__ pos_out,   float* __restrict__ ref_out)
{
    int wave = threadIdx.x >> 6, l = threadIdx.x & 63;
    int bg = blockIdx.y, b = bg >> 2, g = bg & 3;
    int s  = blockIdx.x * 4 + wave;
    int py = s / 28, px = s - py * 28;
    bool has2 = l < 32;
    int c0 = l, c1 = 64 + l;

    const unsigned short* qb = qT + (size_t)b * HW * NC + g * GC;

    float h0 = 0.f, h1 = 0.f;
    #pragma unroll
    for (int ky = 0; ky < 3; ky++) {
        int yy = py * 2 - 1 + ky;
        if (yy < 0 || yy >= H) continue;
        #pragma unroll
        for (int kx = 0; kx < 3; kx++) {
            int xx = px * 2 - 1 + kx;
            if (xx < 0 || xx >= W) continue;
            const unsigned short* row = qb + (size_t)(yy * W + xx) * NC;
            float w0 = dww[c0 * 9 + ky * 3 + kx];
            h0 = fmaf(bf2f(row[c0]), w0, h0);
            if (has2) {
                float w1 = dww[c1 * 9 + ky * 3 + kx];
                h1 = fmaf(bf2f(row[c1]), w1, h1);
            }
        }
    }
    h0 += dwb[c0];
    if (has2) h1 += dwb[c1];

    float mu = wred_sum(h0 + (has2 ? h1 : 0.f)) * (1.f / GC);
    float d0 = h0 - mu, d1 = h1 - mu;
    float var = wred_sum(d0 * d0 + (has2 ? d1 * d1 : 0.f)) * (1.f / GC);
    float rstd = rsqrtf(var + 1e-5f);

    float hn0 = d0 * rstd * lng[c0] + lnb[c0];
    float ge0 = 0.5f * hn0 * (1.f + erff(hn0 * 0.70710678118654752f));
    float ge1 = 0.f;
    if (has2) {
        float hn1 = d1 * rstd * lng[c1] + lnb[c1];
        ge1 = 0.5f * hn1 * (1.f + erff(hn1 * 0.70710678118654752f));
    }

    float offy = wred_sum(ge0 * pww[c0] + (has2 ? ge1 * pww[c1] : 0.f));
    float offx = wred_sum(ge0 * pww[GC + c0] + (has2 ? ge1 * pww[GC + c1] : 0.f));

    if (l == 0) {
        float ry = (2.f * py + 1.f) / 27.f - 1.f;
        float rx = (2.f * px + 1.f) / 27.f - 1.f;
        size_t idx = ((size_t)bg * NPTS + s) * 2;
        pos_out[idx]     = tanhf(offy) * (1.f / 27.f) + ry;
        pos_out[idx + 1] = tanhf(offx) * (1.f / 27.f) + rx;
        ref_out[idx]     = ry;
        ref_out[idx + 1] = rx;
    }
}

// ---------------------------------------------------------------------------
// Bilinear grid sample from xT (bf16, [b][hw][384]) -> xsT [b][pt][384] bf16.
// ---------------------------------------------------------------------------
__global__ __launch_bounds__(256) void sample_kernel(
    const unsigned short* __restrict__ xT, const float* __restrict__ pos,
    unsigned short* __restrict__ xsT)
{
    int bg = blockIdx.y;
    int b  = bg >> 2, g = bg & 3;
    int s  = blockIdx.x * 8 + (threadIdx.x >> 5);
    int l  = threadIdx.x & 31;

    const float* pg = pos + ((size_t)bg * NPTS + s) * 2;
    float py = pg[0], px = pg[1];
    float gx = (px + 1.f) * 27.5f;
    float gy = (py + 1.f) * 27.5f;
    float x0f = floorf(gx), y0f = floorf(gy);
    int ix0 = (int)x0f, iy0 = (int)y0f;
    int ix1 = ix0 + 1,  iy1 = iy0 + 1;
    float wx1 = gx - x0f, wx0 = 1.f - wx1;
    float wy1 = gy - y0f, wy0 = 1.f - wy1;
    bool vx0 = (ix0 >= 0) && (ix0 < W);
    bool vx1 = (ix1 >= 0) && (ix1 < W);
    bool vy0 = (iy0 >= 0) && (iy0 < H);
    bool vy1 = (iy1 >= 0) && (iy1 < H);
    int cx0 = vx0 ? ix0 : 0, cx1 = vx1 ? ix1 : 0;
    int cy0 = vy0 ? iy0 : 0, cy1 = vy1 ? iy1 : 0;
    float w00 = (vx0 && vy0) ? wx0 * wy0 : 0.f;
    float w01 = (vx1 && vy0) ? wx1 * wy0 : 0.f;
    float w10 = (vx0 && vy1) ? wx0 * wy1 : 0.f;
    float w11 = (vx1 && vy1) ? wx1 * wy1 : 0.f;

    const unsigned short* xb = xT + (size_t)b * HW * NC + g * GC;
    const unsigned short* r00 = xb + (size_t)(cy0 * W + cx0) * NC;
    const unsigned short* r01 = xb + (size_t)(cy0 * W + cx1) * NC;
    const unsigned short* r10 = xb + (size_t)(cy1 * W + cx0) * NC;
    const unsigned short* r11 = xb + (size_t)(cy1 * W + cx1) * NC;
    unsigned short* orow = xsT + ((size_t)b * NPTS + s) * NC + g * GC;
    #pragma unroll
    for (int ci = 0; ci < 3; ci++) {
        int c = l + ci * 32;
        float val = bf2f(r00[c]) * w00 + bf2f(r01[c]) * w01
                  + bf2f(r10[c]) * w10 + bf2f(r11[c]) * w11;
        orow[c] = f2bf(val);
    }
}

// ---------------------------------------------------------------------------
// Fused flash attention v5: round-6 LDS-staged structure + 4 query-sets per
// wave (64 q/wave, 256 q/block — every K/V fragment feeds 4 MFMAs) +
// software-pipelined staging (chunk ci+1 global loads issued before compute
// of chunk ci; write waits land after a full compute phase of latency).
// No max-subtraction (shift-invariant, |s| small); scale pre-folded into Q.
// ---------------------------------------------------------------------------
#define KS_STRIDE 56    // shorts: 48 chans + 8 pad
#define VS_STRIDE 136   // shorts: 128 keys + 8 pad
#define PS_STRIDE 40    // shorts: 32 keys + 8 pad (per-set pane)

__device__ inline short8 scale8(short8 v, float s) {
    short8 r;
    #pragma unroll
    for (int j = 0; j < 8; j++)
        r[j] = (short)f2bf(bf2f((unsigned short)v[j]) * s);
    return r;
}

__global__ __launch_bounds__(256) void attn_mfma(
    const unsigned short* __restrict__ qT, const unsigned short* __restrict__ kt,
    const unsigned short* __restrict__ vt, unsigned short* __restrict__ aoT)
{
    __shared__ __align__(16) unsigned short smem[23936];   // 47872 B
    unsigned short* Ks = smem;                 // 128*56 = 7168
    unsigned short* Vs = Ks + 128 * KS_STRIDE; // 48*136 = 6528
    unsigned short* Ps = Vs + 48 * VS_STRIDE;  // 16 panes * 16*40 = 10240

    int t    = threadIdx.x;
    int wave = t >> 6, lane = t & 63;
    int quad = lane >> 4, col = lane & 15;

    int bh = blockIdx.y;
    int b  = bh >> 3, h = bh & 7;
    int m0 = blockIdx.x * 256;
    const unsigned short* KT = kt + (size_t)b * NPTS * NC + h * HC;
    const unsigned short* VT = vt + ((size_t)b * NC + h * HC) * NPTS;

    const float scale = 0.14433756729740643f;   // 48^-0.5
    const short8 z8 = {0,0,0,0,0,0,0,0};

    // ---- Q B-fragments, 4 sets, pre-scaled ----
    int gmq[4];
    short8 qb0[4], qb1[4];
    #pragma unroll
    for (int set = 0; set < 4; set++) {
        int gm = m0 + wave * 64 + set * 16 + col;
        gmq[set] = gm;
        int cg = gm < HW ? gm : HW - 1;
        const unsigned short* r0 = qT + ((size_t)b * HW + cg) * NC + h * HC;
        qb0[set] = scale8(*(const short8*)&r0[quad * 8], scale);
        qb1[set] = (quad < 2) ? scale8(*(const short8*)&r0[32 + quad * 8], scale) : z8;
    }

    unsigned short* paneW = Ps + wave * 4 * 16 * PS_STRIDE;

    float l_acc[4] = {0.f, 0.f, 0.f, 0.f};
    f32x4 acc_o[4][3];
    #pragma unroll
    for (int set = 0; set < 4; set++)
        #pragma unroll
        for (int ct = 0; ct < 3; ct++) acc_o[set][ct] = (f32x4){0.f, 0.f, 0.f, 0.f};

    // staging identity: K key = t>>1 (0..127), parts (t&1)*3 ..+2
    int skey  = t >> 1;
    int spart = (t & 1) * 3;
    // V: li = t + i*256 -> chan = li>>4, part = li&15
    short8 kreg[3], vreg[3];

    // ---- prologue: load chunk 0 ----
    {
        bool kv = skey < NPTS;   // always true for chunk 0
        const unsigned short* krow = KT + (size_t)skey * NC + spart * 8;
        #pragma unroll
        for (int i = 0; i < 3; i++) kreg[i] = kv ? *(const short8*)(krow + i * 8) : z8;
        #pragma unroll
        for (int i = 0; i < 3; i++) {
            int li = t + i * 256;
            int chan = li >> 4, part = li & 15;
            vreg[i] = *(const short8*)&VT[(size_t)chan * NPTS + part * 8];
        }
    }

    for (int ci = 0; ci < 7; ci++) {
        int k0 = ci * 128;

        // ---- write staged regs -> LDS ----
        #pragma unroll
        for (int i = 0; i < 3; i++)
            *(short8*)&Ks[skey * KS_STRIDE + (spart + i) * 8] = kreg[i];
        #pragma unroll
        for (int i = 0; i < 3; i++) {
            int li = t + i * 256;
            int chan = li >> 4, part = li & 15;
            *(short8*)&Vs[chan * VS_STRIDE + part * 8] = vreg[i];
        }
        __syncthreads();

        // ---- issue next chunk's global loads (latency hidden by compute) --
        if (ci < 6) {
            int nk0 = k0 + 128;
            bool kv = nk0 + skey < NPTS;
            const unsigned short* krow = KT + (size_t)(nk0 + skey) * NC + spart * 8;
            #pragma unroll
            for (int i = 0; i < 3; i++) kreg[i] = kv ? *(const short8*)(krow + i * 8) : z8;
            #pragma unroll
            for (int i = 0; i < 3; i++) {
                int li = t + i * 256;
                int chan = li >> 4, part = li & 15;
                vreg[i] = (nk0 + part * 8 < NPTS)
                    ? *(const short8*)&VT[(size_t)chan * NPTS + nk0 + part * 8] : z8;
            }
        }

        // ---- compute chunk ci ----
        #pragma unroll
        for (int s2 = 0; s2 < 4; s2++) {
            #pragma unroll
            for (int jth = 0; jth < 2; jth++) {
                int jt = s2 * 2 + jth;
                int keyl = jt * 16 + col;
                short8 kb0 = *(const short8*)&Ks[keyl * KS_STRIDE + quad * 8];
                short8 kb1 = (quad < 2)
                    ? *(const short8*)&Ks[keyl * KS_STRIDE + 32 + quad * 8] : z8;
                bool valid = (k0 + jt * 16) < NPTS;         // tile-uniform
                #pragma unroll
                for (int set = 0; set < 4; set++) {
                    f32x4 sa = {0.f, 0.f, 0.f, 0.f};
                    sa = __builtin_amdgcn_mfma_f32_16x16x32_bf16(kb0, qb0[set], sa, 0, 0, 0);
                    sa = __builtin_amdgcn_mfma_f32_16x16x32_bf16(kb1, qb1[set], sa, 0, 0, 0);
                    us4 p = {0, 0, 0, 0};
                    if (valid) {
                        #pragma unroll
                        for (int r = 0; r < 4; r++) {
                            float pv = __expf(sa[r]);
                            l_acc[set] += pv;
                            p[r] = f2bf_t(pv);
                        }
                    }
                    *(us4*)&paneW[set * 16 * PS_STRIDE + col * PS_STRIDE + jth * 16 + quad * 4] = p;
                }
            }
            // ---- PV for these 32 keys ----
            short8 pb[4];
            #pragma unroll
            for (int set = 0; set < 4; set++)
                pb[set] = *(const short8*)&paneW[set * 16 * PS_STRIDE + col * PS_STRIDE + quad * 8];
            #pragma unroll
            for (int ct = 0; ct < 3; ct++) {
                short8 va = *(const short8*)&Vs[(ct * 16 + col) * VS_STRIDE + s2 * 32 + quad * 8];
                #pragma unroll
                for (int set = 0; set < 4; set++)
                    acc_o[set][ct] = __builtin_amdgcn_mfma_f32_16x16x32_bf16(
                        va, pb[set], acc_o[set][ct], 0, 0, 0);
            }
        }
        __syncthreads();   // LDS consumed; next write safe
    }

    // ---- epilogue: cross-quad l reduction, normalize, us4 stores ----
    #pragma unroll
    for (int set = 0; set < 4; set++) {
        float l = l_acc[set];
        l += __shfl_xor(l, 16);
        l += __shfl_xor(l, 32);
        float inv = 1.f / l;
        int gm = gmq[set];
        if (gm < HW) {
            unsigned short* orow = aoT + ((size_t)b * HW + gm) * NC + h * HC;
            #pragma unroll
            for (int ct = 0; ct < 3; ct++) {
                us4 p;
                #pragma unroll
                for (int r = 0; r < 4; r++) p[r] = f2bf(acc_o[set][ct][r] * inv);
                *(us4*)&orow[ct * 16 + quad * 4] = p;
            }
        }
    }
}

// ---------------------------------------------------------------------------
extern "C" void kernel_launch(void* const* d_in, const int* in_sizes, int n_in,
                              void* d_out, int out_size, void* d_ws, size_t ws_size,
                              hipStream_t stream)
{
    const float* x   = (const float*)d_in[0];
    const float* Wq  = (const float*)d_in[1];
    const float* bq  = (const float*)d_in[2];
    const float* Wk  = (const float*)d_in[3];
    const float* bk  = (const float*)d_in[4];
    const float* Wv  = (const float*)d_in[5];
    const float* bv  = (const float*)d_in[6];
    const float* Wo  = (const float*)d_in[7];
    const float* bo  = (const float*)d_in[8];
    const float* dww = (const float*)d_in[9];
    const float* dwb = (const float*)d_in[10];
    const float* lng = (const float*)d_in[11];
    const float* lnb = (const float*)d_in[12];
    const float* pww = (const float*)d_in[13];

    float* out     = (float*)d_out;
    float* y_out   = out;
    float* pos_out = out + (size_t)BATCH * NC * HW;
    float* ref_out = pos_out + (size_t)BATCH * NG * NPTS * 2;

    const size_t NBIG = (size_t)BATCH * NC * HW;    // 9,633,792
    const size_t NSML = (size_t)BATCH * NC * NPTS;  // 2,408,448

    unsigned short* xT   = (unsigned short*)d_ws;
    unsigned short* qT   = xT   + NBIG;
    unsigned short* xsT  = qT   + NBIG;
    unsigned short* kt_w = xsT  + NSML;
    unsigned short* vt_w = kt_w + NSML;
    unsigned short* aoT  = vt_w + NSML;
    unsigned short* wqb  = aoT  + NBIG;
    unsigned short* wob  = wqb + NC * NC;
    unsigned short* wkv  = wob + NC * NC;          // 768 x 384

    transpose_cvt<<<dim3(49, 6, BATCH), 256, 0, stream>>>(x, xT);
    wcvt<<<dim3(144, 4), 256, 0, stream>>>(Wq, Wk, Wv, Wo, wqb, wkv, wob);
    gemm_bf16<2><<<dim3(25, 3, BATCH), 256, 0, stream>>>(
        wqb, bq, nullptr, xT, nullptr, qT, nullptr, HW);
    offset_kernel<<<dim3(196, BATCH * NG), 256, 0, stream>>>(
        qT, dww, dwb, lng, lnb, pww, pos_out, ref_out);
    sample_kernel<<<dim3(98, BATCH * NG), 256, 0, stream>>>(xT, pos_out, xsT);
    gemm_bf16<4><<<dim3(7, 6, BATCH), 256, 0, stream>>>(
        wkv, bk, bv, xsT, nullptr, kt_w, vt_w, NPTS);
    attn_mfma<<<dim3((HW + 255) / 256, BATCH * NH), 256, 0, stream>>>(
        qT, kt_w, vt_w, aoT);
    gemm_bf16<0><<<dim3(25, 3, BATCH), 256, 0, stream>>>(
        wob, bo, nullptr, aoT, y_out, nullptr, nullptr, HW);
}